// Round 1
// baseline (3574.278 us; speedup 1.0000x reference)
//
#include <hip/hip_runtime.h>
#include <cmath>

#define NB 64
#define NP 196
#define NE 2048
#define NA 512
#define ND 512
#define NEMB 512
#define NV 10000
#define NL 52
#define NT 51

typedef unsigned short bf16_t;
typedef __attribute__((ext_vector_type(8))) short bf16x8;
typedef __attribute__((ext_vector_type(4))) float f32x4;

__device__ inline unsigned short f2bf(float f){
  unsigned int x = __float_as_uint(f);
  unsigned int r = x + 0x7fffu + ((x>>16)&1u);
  return (unsigned short)(r>>16);
}
__device__ inline float bf2f(unsigned short u){ return __uint_as_float(((unsigned int)u)<<16); }
__device__ inline float sigm(float x){ return 1.f/(1.f+expf(-x)); }

// ---------------- sort (stable descending by length) ----------------
__global__ void k_sort(const int* __restrict__ cap_len, const int* __restrict__ caps,
                       int* __restrict__ order, int* __restrict__ dlen, int* __restrict__ caps_s,
                       float* __restrict__ out_caps, float* __restrict__ out_dlen, float* __restrict__ out_order){
  __shared__ int len_s[NB];
  __shared__ int ord_s[NB];
  int t = threadIdx.x; // 64 threads
  len_s[t] = cap_len[t];
  __syncthreads();
  int li = len_s[t]; int rank = 0;
  for(int j=0;j<NB;j++){ int lj = len_s[j]; rank += ((lj > li) || (lj==li && j<t)) ? 1 : 0; }
  ord_s[rank] = t;
  __syncthreads();
  int ob = ord_s[t];
  order[t] = ob; out_order[t] = (float)ob;
  int ls = len_s[ob]; dlen[t] = ls-1; out_dlen[t] = (float)(ls-1);
  for(int l=0;l<NL;l++){ int cv = caps[ob*NL + l]; caps_s[t*NL+l]=cv; out_caps[t*NL+l] = (float)cv; }
}

// ---------------- f32 -> bf16 converters ----------------
__global__ __launch_bounds__(256) void k_cvt4(const float* __restrict__ src, bf16_t* __restrict__ dst, int n4){
  int i = blockIdx.x*blockDim.x + threadIdx.x;
  int stride = gridDim.x*blockDim.x;
  for(; i<n4; i+=stride){
    float4 v = ((const float4*)src)[i];
    unsigned long long p = (unsigned long long)f2bf(v.x)
        | ((unsigned long long)f2bf(v.y)<<16)
        | ((unsigned long long)f2bf(v.z)<<32)
        | ((unsigned long long)f2bf(v.w)<<48);
    ((unsigned long long*)dst)[i] = p;
  }
}

__global__ __launch_bounds__(256) void k_cvt2d4(const float* __restrict__ src, int rows, int cols,
                                                bf16_t* __restrict__ dst, int dld, int doff){
  int n4 = rows*cols/4;
  int c4n = cols/4;
  int i = blockIdx.x*blockDim.x + threadIdx.x;
  int stride = gridDim.x*blockDim.x;
  for(; i<n4; i+=stride){
    int r = i / c4n, c4 = i % c4n;
    float4 v = ((const float4*)src)[i];
    unsigned long long p = (unsigned long long)f2bf(v.x)
        | ((unsigned long long)f2bf(v.y)<<16)
        | ((unsigned long long)f2bf(v.z)<<32)
        | ((unsigned long long)f2bf(v.w)<<48);
    *(unsigned long long*)(dst + (size_t)r*dld + doff + c4*4) = p;
  }
}

// ---------------- mean over P (sorted output) ----------------
__global__ __launch_bounds__(256) void k_mean(const float* __restrict__ enc, const int* __restrict__ order,
                                              bf16_t* __restrict__ me_s){
  int bs = blockIdx.x; int ec = blockIdx.y; int e = ec*256 + threadIdx.x;
  int ob = order[bs];
  const float* p = enc + (size_t)ob*NP*NE + e;
  float acc=0.f;
  for(int q=0;q<NP;q++) acc += p[(size_t)q*NE];
  me_s[(size_t)bs*NE + e] = f2bf(acc * (1.0f/NP));
}

// ---------------- big one-time GEMM: att1 = enc @ W_ea^T + b_ea ----------------
// C[m,n] = sum_k A[m,k]*W[n,k], M=12544, N=512, K=2048
__global__ __launch_bounds__(256) void k_att1(const bf16_t* __restrict__ Aenc, const bf16_t* __restrict__ Wea,
                                              const float* __restrict__ b_ea, bf16_t* __restrict__ att1){
  __shared__ bf16_t As[128][72];
  __shared__ bf16_t Bs[128][72];
  int mblk = blockIdx.x, nblk = blockIdx.y;
  int tid = threadIdx.x;
  int w = tid>>6, l = tid&63;
  int moff = (w>>1)*64, noff = (w&1)*64;
  f32x4 acc[4][4] = {};
  const int mbase = mblk*128, nbase = nblk*128;
  for(int k0=0; k0<2048; k0+=64){
    __syncthreads();
    for(int u=0;u<4;u++){
      int lin = u*256 + tid; int row = lin>>3; int col = (lin&7)*8;
      *(bf16x8*)(&As[row][col]) = *(const bf16x8*)(Aenc + (size_t)(mbase+row)*2048 + k0 + col);
      *(bf16x8*)(&Bs[row][col]) = *(const bf16x8*)(Wea + (size_t)(nbase+row)*2048 + k0 + col);
    }
    __syncthreads();
    for(int kk=0;kk<2;kk++){
      bf16x8 af[4], bfr[4];
      for(int m=0;m<4;m++) af[m] = *(bf16x8*)(&As[moff + 16*m + (l&15)][kk*32 + (l>>4)*8]);
      for(int n=0;n<4;n++) bfr[n] = *(bf16x8*)(&Bs[noff + 16*n + (l&15)][kk*32 + (l>>4)*8]);
      for(int m=0;m<4;m++)
        for(int n=0;n<4;n++)
          acc[m][n] = __builtin_amdgcn_mfma_f32_16x16x32_bf16(af[m], bfr[n], acc[m][n], 0,0,0);
    }
  }
  for(int m=0;m<4;m++) for(int n=0;n<4;n++){
    int col = nbase + noff + 16*n + (l&15);
    float bias = b_ea[col];
    for(int r=0;r<4;r++){
      int row = mbase + moff + 16*m + (l>>4)*4 + r;
      att1[(size_t)row*512 + col] = f2bf(acc[m][n][r] + bias);
    }
  }
}

// ---------------- small-M (64) GEMM with K-split: partials ----------------
// part[ks][b][n] = sum_{k in slice ks} A[b,k]*W[n,k]
template<int KSL>
__global__ __launch_bounds__(256) void k_gemm_part(const bf16_t* __restrict__ Ax, int lda,
        const bf16_t* __restrict__ W, int ldw, float* __restrict__ part, int N){
  __shared__ bf16_t As[64][KSL+8];
  int ntile = blockIdx.x, ks = blockIdx.y;
  int tid = threadIdx.x; int w = tid>>6, l = tid&63;
  int k0 = ks*KSL;
  constexpr int UPR = KSL/8;           // 16B units per row
  constexpr int UPT = 64*UPR/256;      // units per thread
  for(int u=0;u<UPT;u++){
    int lin = u*256 + tid; int row = lin/UPR; int col = (lin%UPR)*8;
    *(bf16x8*)(&As[row][col]) = *(const bf16x8*)(Ax + (size_t)row*lda + k0 + col);
  }
  __syncthreads();
  f32x4 acc[4][4] = {};
  int nbase = ntile*256 + w*64;
  for(int kk=0; kk<KSL/32; kk++){
    bf16x8 af[4], bfr[4];
    for(int m=0;m<4;m++) af[m] = *(bf16x8*)(&As[16*m + (l&15)][kk*32 + (l>>4)*8]);
    for(int n=0;n<4;n++) bfr[n] = *(const bf16x8*)(W + (size_t)(nbase + 16*n + (l&15))*ldw + k0 + kk*32 + (l>>4)*8);
    for(int m=0;m<4;m++)
      for(int n=0;n<4;n++)
        acc[m][n] = __builtin_amdgcn_mfma_f32_16x16x32_bf16(af[m], bfr[n], acc[m][n], 0,0,0);
  }
  float* po = part + (size_t)ks*64*N;
  for(int m=0;m<4;m++) for(int n=0;n<4;n++){
    int col = nbase + 16*n + (l&15);
    for(int r=0;r<4;r++){
      int row = 16*m + (l>>4)*4 + r;
      po[(size_t)row*N + col] = acc[m][n][r];
    }
  }
}

// ---------------- combine init partials -> h0 (bf16 into xh), c0 (f32) ----------------
__global__ __launch_bounds__(256) void k_init_fin(const float* __restrict__ part,
        const float* __restrict__ b_ih_, const float* __restrict__ b_ic_,
        float* __restrict__ c, bf16_t* __restrict__ xh){
  int idx = blockIdx.x*256 + threadIdx.x;  // 0..32767
  int b_ = idx>>9, d = idx&511;
  float h = b_ih_[d], cc = b_ic_[d];
  for(int ks=0;ks<4;ks++){
    const float* p = part + (size_t)ks*64*1024 + (size_t)b_*1024;
    h += p[d]; cc += p[512+d];
  }
  c[idx] = cc;
  xh[(size_t)b_*3072 + 2560 + d] = f2bf(h);
}

// ---------------- LSTM cell: combine gates partials, update h/c ----------------
__global__ __launch_bounds__(256) void k_cell(const float* __restrict__ part,
        const float* __restrict__ b_ih, const float* __restrict__ b_hh,
        float* __restrict__ c, bf16_t* __restrict__ xh, bf16_t* __restrict__ h2b,
        const int* __restrict__ dlen, int t){
  int idx = blockIdx.x*256 + threadIdx.x; // 0..32767
  int b_ = idx>>9, d = idx&511;
  float gi = b_ih[d] + b_hh[d];
  float gf = b_ih[512+d] + b_hh[512+d];
  float gg = b_ih[1024+d] + b_hh[1024+d];
  float go = b_ih[1536+d] + b_hh[1536+d];
  for(int ks=0;ks<8;ks++){
    const float* p = part + (size_t)ks*64*2048 + (size_t)b_*2048;
    gi += p[d]; gf += p[512+d]; gg += p[1024+d]; go += p[1536+d];
  }
  float c2 = sigm(gf)*c[idx] + sigm(gi)*tanhf(gg);
  float h2 = sigm(go)*tanhf(c2);
  bool mask = t < dlen[b_];
  if(mask){
    c[idx] = c2;
    xh[(size_t)b_*3072 + 2560 + d] = f2bf(h2);
  }
  h2b[idx] = f2bf(h2);
}

// ---------------- post: preds (from h2) and att2|gpre (from h) ----------------
__global__ __launch_bounds__(256) void k_post(const bf16_t* __restrict__ h2b, const bf16_t* __restrict__ xh,
     const bf16_t* __restrict__ Wfc, const float* __restrict__ b_fc,
     const bf16_t* __restrict__ Wdafb, const float* __restrict__ b_da, const float* __restrict__ b_fb,
     const int* __restrict__ dlen, float* __restrict__ preds_out, float* __restrict__ a2g,
     int t, int preds_blocks){
  __shared__ bf16_t As[64][520];
  bool isP = (int)blockIdx.x < preds_blocks;
  const bf16_t* Asrc = isP ? h2b : (xh + 2560);
  int lda = isP ? 512 : 3072;
  int tid = threadIdx.x; int w = tid>>6, l = tid&63;
  for(int u=0;u<16;u++){
    int lin = u*256 + tid; int row = lin>>6; int col = (lin&63)*8;
    *(bf16x8*)(&As[row][col]) = *(const bf16x8*)(Asrc + (size_t)row*lda + col);
  }
  __syncthreads();
  f32x4 acc[4][4] = {};
  int nbase = (isP ? (int)blockIdx.x : ((int)blockIdx.x - preds_blocks))*256 + w*64;
  const bf16_t* Wp = isP ? Wfc : Wdafb;
  int Nw = isP ? NV : 2560;
  for(int kk=0;kk<16;kk++){
    bf16x8 af[4], bfr[4];
    for(int m=0;m<4;m++) af[m] = *(bf16x8*)(&As[16*m+(l&15)][kk*32+(l>>4)*8]);
    for(int n=0;n<4;n++){
      int rowW = nbase + 16*n + (l&15); if(rowW >= Nw) rowW = Nw-1;
      bfr[n] = *(const bf16x8*)(Wp + (size_t)rowW*512 + kk*32 + (l>>4)*8);
    }
    for(int m=0;m<4;m++)
      for(int n=0;n<4;n++)
        acc[m][n] = __builtin_amdgcn_mfma_f32_16x16x32_bf16(af[m], bfr[n], acc[m][n], 0,0,0);
  }
  if(isP){
    for(int m=0;m<4;m++) for(int n=0;n<4;n++){
      int col = nbase + 16*n + (l&15);
      if(col < NV){
        float bias = b_fc[col];
        for(int r=0;r<4;r++){
          int b_ = 16*m + (l>>4)*4 + r;
          float mf = (t < dlen[b_]) ? 1.f : 0.f;
          preds_out[((size_t)b_*NT + t)*NV + col] = (acc[m][n][r] + bias)*mf;
        }
      }
    }
  } else {
    for(int m=0;m<4;m++) for(int n=0;n<4;n++){
      int col = nbase + 16*n + (l&15);
      float bias = (col < 512) ? b_da[col] : b_fb[col-512];
      for(int r=0;r<4;r++){
        int b_ = 16*m + (l>>4)*4 + r;
        a2g[(size_t)b_*2560 + col] = acc[m][n][r] + bias;
      }
    }
  }
}

// ---------------- attention scores + softmax + emb staging ----------------
__global__ __launch_bounds__(256) void k_att(const bf16_t* __restrict__ att1b,
    const float* __restrict__ a2g, const float* __restrict__ w_fa, const float* __restrict__ b_fa,
    const int* __restrict__ order, const int* __restrict__ dlen, const int* __restrict__ caps_s,
    const float* __restrict__ emb_table, float* __restrict__ alpha_ws, float* __restrict__ alphas_out,
    bf16_t* __restrict__ xh, int t){
  int b_ = blockIdx.x; int tid = threadIdx.x;
  __shared__ float att2s[512];
  __shared__ float wfas[512];
  __shared__ float es[196];
  __shared__ float red[8];
  for(int i=tid;i<512;i+=256){ att2s[i] = a2g[(size_t)b_*2560 + i]; wfas[i] = w_fa[i]; }
  __syncthreads();
  int w = tid>>6, l = tid&63;
  int ob = order[b_];
  float bfa0 = b_fa[0];
  for(int p=w; p<NP; p+=4){
    const bf16_t* a1 = att1b + ((size_t)ob*NP + p)*512;
    float s = 0.f;
    for(int q=0;q<8;q++){
      int i = l + q*64;
      float v = bf2f(a1[i]) + att2s[i];
      v = v>0.f ? v : 0.f;
      s += v*wfas[i];
    }
    for(int off=32;off;off>>=1) s += __shfl_down(s, off);
    if(l==0) es[p] = s + bfa0;
  }
  __syncthreads();
  float v = (tid<NP)? es[tid] : -1e30f;
  float m = v;
  for(int off=32;off;off>>=1) m = fmaxf(m, __shfl_down(m, off));
  if(l==0) red[w] = m;
  __syncthreads();
  if(tid==0){ float mm = red[0]; for(int i=1;i<4;i++) mm = fmaxf(mm, red[i]); red[4] = mm; }
  __syncthreads();
  float mx = red[4];
  float ex = (tid<NP)? expf(v - mx) : 0.f;
  float s2 = ex;
  for(int off=32;off;off>>=1) s2 += __shfl_down(s2, off);
  if(l==0) red[w] = s2;
  __syncthreads();
  if(tid==0){ red[5] = 1.f/(red[0]+red[1]+red[2]+red[3]); }
  __syncthreads();
  float inv = red[5];
  bool mask = t < dlen[b_];
  if(tid<NP){
    float al = ex*inv;
    alpha_ws[b_*NP + tid] = al;
    alphas_out[((size_t)b_*NT + t)*NP + tid] = mask ? al : 0.f;
  }
  // stage embedding for this step into xh[:, 0:512]
  int cap = caps_s[b_*NL + t];
  for(int d=tid; d<512; d+=256)
    xh[(size_t)b_*3072 + d] = f2bf(emb_table[(size_t)cap*NEMB + d]);
}

// ---------------- awe = (alpha-weighted enc) * sigmoid(gpre) ----------------
__global__ __launch_bounds__(256) void k_awe(const bf16_t* __restrict__ encb, const float* __restrict__ alpha_ws,
   const float* __restrict__ a2g, const int* __restrict__ order, bf16_t* __restrict__ xh){
  int b_ = blockIdx.x; int jc = blockIdx.y; int tid = threadIdx.x;
  __shared__ float al[196];
  for(int i=tid;i<NP;i+=256) al[i] = alpha_ws[b_*NP + i];
  __syncthreads();
  int ob = order[b_];
  int j = jc*512 + tid*2;
  const bf16_t* ep = encb + (size_t)ob*NP*NE + j;
  float a0=0.f, a1=0.f;
  for(int p=0;p<NP;p++){
    unsigned int u = *(const unsigned int*)(ep + (size_t)p*NE);
    float alp = al[p];
    a0 += alp*__uint_as_float(u<<16);
    a1 += alp*__uint_as_float(u & 0xffff0000u);
  }
  float g0 = sigm(a2g[(size_t)b_*2560 + 512 + j]);
  float g1 = sigm(a2g[(size_t)b_*2560 + 512 + j + 1]);
  xh[(size_t)b_*3072 + 512 + j]     = f2bf(g0*a0);
  xh[(size_t)b_*3072 + 512 + j + 1] = f2bf(g1*a1);
}

// ---------------- launcher ----------------
extern "C" void kernel_launch(void* const* d_in, const int* in_sizes, int n_in,
                              void* d_out, int out_size, void* d_ws, size_t ws_size,
                              hipStream_t stream){
  (void)in_sizes; (void)n_in; (void)out_size; (void)ws_size;
  const float* encoder_out      = (const float*)d_in[0];
  const int*   encoded_captions = (const int*)d_in[1];
  const int*   caption_lengths  = (const int*)d_in[2];
  const float* W_ea = (const float*)d_in[3];  const float* b_ea = (const float*)d_in[4];
  const float* W_da = (const float*)d_in[5];  const float* b_da = (const float*)d_in[6];
  const float* w_fa = (const float*)d_in[7];  const float* b_fa = (const float*)d_in[8];
  const float* emb_table = (const float*)d_in[9];
  const float* W_ih = (const float*)d_in[10]; const float* b_ih = (const float*)d_in[11];
  const float* W_hh = (const float*)d_in[12]; const float* b_hh = (const float*)d_in[13];
  const float* W_init_h = (const float*)d_in[14]; const float* b_init_h = (const float*)d_in[15];
  const float* W_init_c = (const float*)d_in[16]; const float* b_init_c = (const float*)d_in[17];
  const float* W_fb = (const float*)d_in[18]; const float* b_fb = (const float*)d_in[19];
  const float* W_fc = (const float*)d_in[20]; const float* b_fc = (const float*)d_in[21];

  // d_out layout (all f32): preds | caps | dec_len | alphas | order
  float* out_preds = (float*)d_out;
  float* out_caps  = out_preds + (size_t)NB*NT*NV;
  float* out_dlen  = out_caps + NB*NL;
  float* out_alph  = out_dlen + NB;
  float* out_order = out_alph + (size_t)NB*NT*NP;

  char* ws = (char*)d_ws;
  size_t off = 0;
  auto alloc = [&](size_t bytes)->size_t{ size_t r = off; off += (bytes + 255) & ~(size_t)255; return r; };
  bf16_t* enc_b   = (bf16_t*)(ws + alloc((size_t)12544*2048*2));
  bf16_t* att1_b  = (bf16_t*)(ws + alloc((size_t)12544*512*2));
  bf16_t* Wea_b   = (bf16_t*)(ws + alloc((size_t)512*2048*2));
  bf16_t* Wdafb_b = (bf16_t*)(ws + alloc((size_t)2560*512*2));
  bf16_t* Wcat_b  = (bf16_t*)(ws + alloc((size_t)2048*3072*2));
  bf16_t* Winit_b = (bf16_t*)(ws + alloc((size_t)1024*2048*2));
  bf16_t* Wfc_b   = (bf16_t*)(ws + alloc((size_t)10000*512*2));
  bf16_t* me_b    = (bf16_t*)(ws + alloc((size_t)64*2048*2));
  bf16_t* xh_b    = (bf16_t*)(ws + alloc((size_t)64*3072*2));
  bf16_t* h2_b    = (bf16_t*)(ws + alloc((size_t)64*512*2));
  float*  c_f     = (float*)(ws + alloc((size_t)64*512*4));
  float*  a2g_f   = (float*)(ws + alloc((size_t)64*2560*4));
  float*  gpart   = (float*)(ws + alloc((size_t)8*64*2048*4));
  float*  ipart   = (float*)(ws + alloc((size_t)4*64*1024*4));
  float*  alpha_f = (float*)(ws + alloc((size_t)64*196*4));
  int*    order_i = (int*)(ws + alloc(64*4));
  int*    dlen_i  = (int*)(ws + alloc(64*4));
  int*    caps_i  = (int*)(ws + alloc((size_t)64*52*4));

  k_sort<<<1,64,0,stream>>>(caption_lengths, encoded_captions, order_i, dlen_i, caps_i,
                            out_caps, out_dlen, out_order);
  k_cvt4<<<2048,256,0,stream>>>(encoder_out, enc_b, 12544*2048/4);
  k_cvt4<<<512,256,0,stream>>>(W_ea, Wea_b, 512*2048/4);
  k_cvt4<<<256,256,0,stream>>>(W_da, Wdafb_b, 512*512/4);
  k_cvt4<<<512,256,0,stream>>>(W_fb, Wdafb_b + 512*512, 2048*512/4);
  k_cvt2d4<<<1024,256,0,stream>>>(W_ih, 2048, 2560, Wcat_b, 3072, 0);
  k_cvt2d4<<<512,256,0,stream>>>(W_hh, 2048, 512, Wcat_b, 3072, 2560);
  k_cvt4<<<512,256,0,stream>>>(W_init_h, Winit_b, 512*2048/4);
  k_cvt4<<<512,256,0,stream>>>(W_init_c, Winit_b + 512*2048, 512*2048/4);
  k_cvt4<<<1024,256,0,stream>>>(W_fc, Wfc_b, 10000*512/4);
  k_mean<<<dim3(64,8),256,0,stream>>>(encoder_out, order_i, me_b);
  k_gemm_part<512><<<dim3(4,4),256,0,stream>>>(me_b, 2048, Winit_b, 2048, ipart, 1024);
  k_init_fin<<<128,256,0,stream>>>(ipart, b_init_h, b_init_c, c_f, xh_b);
  k_att1<<<dim3(98,4),256,0,stream>>>(enc_b, Wea_b, b_ea, att1_b);
  // initial att2|gpre from h0 (no preds)
  k_post<<<10,256,0,stream>>>(h2_b, xh_b, Wfc_b, b_fc, Wdafb_b, b_da, b_fb,
                              dlen_i, out_preds, a2g_f, 0, 0);
  for(int t=0;t<NT;t++){
    k_att<<<64,256,0,stream>>>(att1_b, a2g_f, w_fa, b_fa, order_i, dlen_i, caps_i,
                               emb_table, alpha_f, out_alph, xh_b, t);
    k_awe<<<dim3(64,4),256,0,stream>>>(enc_b, alpha_f, a2g_f, order_i, xh_b);
    k_gemm_part<384><<<dim3(8,8),256,0,stream>>>(xh_b, 3072, Wcat_b, 3072, gpart, 2048);
    k_cell<<<128,256,0,stream>>>(gpart, b_ih, b_hh, c_f, xh_b, h2_b, dlen_i, t);
    k_post<<<50,256,0,stream>>>(h2_b, xh_b, Wfc_b, b_fc, Wdafb_b, b_da, b_fb,
                                dlen_i, out_preds, a2g_f, t, 40);
  }
}

// Round 2
// 3425.124 us; speedup vs baseline: 1.0435x; 1.0435x over previous
//
#include <hip/hip_runtime.h>
#include <cmath>

#define NB 64
#define NP 196
#define NE 2048
#define NV 10000
#define NL 52
#define NT 51

typedef unsigned short bf16_t;
typedef __attribute__((ext_vector_type(8))) short bf16x8;
typedef __attribute__((ext_vector_type(4))) float f32x4;

__device__ inline unsigned short f2bf(float f){
  unsigned int x = __float_as_uint(f);
  unsigned int r = x + 0x7fffu + ((x>>16)&1u);
  return (unsigned short)(r>>16);
}
__device__ inline float bf2f(unsigned short u){ return __uint_as_float(((unsigned int)u)<<16); }
__device__ inline float sigm(float x){ return 1.f/(1.f+expf(-x)); }

// ---------------- sort (stable descending by length) + nact ----------------
__global__ void k_sort(const int* __restrict__ cap_len, const int* __restrict__ caps,
                       int* __restrict__ order, int* __restrict__ dlen, int* __restrict__ caps_s,
                       int* __restrict__ nact,
                       float* __restrict__ out_caps, float* __restrict__ out_dlen, float* __restrict__ out_order){
  __shared__ int len_s[NB];
  __shared__ int ord_s[NB];
  __shared__ int dls[NB];
  int t = threadIdx.x; // 64 threads
  len_s[t] = cap_len[t];
  __syncthreads();
  int li = len_s[t]; int rank = 0;
  for(int j=0;j<NB;j++){ int lj = len_s[j]; rank += ((lj > li) || (lj==li && j<t)) ? 1 : 0; }
  ord_s[rank] = t;
  __syncthreads();
  int ob = ord_s[t];
  order[t] = ob; out_order[t] = (float)ob;
  int ls = len_s[ob]; dlen[t] = ls-1; out_dlen[t] = (float)(ls-1); dls[t] = ls-1;
  for(int l=0;l<NL;l++){ int cv = caps[ob*NL + l]; caps_s[t*NL+l]=cv; out_caps[t*NL+l] = (float)cv; }
  __syncthreads();
  if(t < NT){
    int cnt=0;
    for(int b=0;b<NB;b++) cnt += (dls[b] > t) ? 1 : 0;
    nact[t] = cnt;
  }
}

// ---------------- f32 -> bf16 converters ----------------
__global__ __launch_bounds__(256) void k_cvt4(const float* __restrict__ src, bf16_t* __restrict__ dst, int n4){
  int i = blockIdx.x*blockDim.x + threadIdx.x;
  int stride = gridDim.x*blockDim.x;
  for(; i<n4; i+=stride){
    float4 v = ((const float4*)src)[i];
    unsigned long long p = (unsigned long long)f2bf(v.x)
        | ((unsigned long long)f2bf(v.y)<<16)
        | ((unsigned long long)f2bf(v.z)<<32)
        | ((unsigned long long)f2bf(v.w)<<48);
    ((unsigned long long*)dst)[i] = p;
  }
}

__global__ __launch_bounds__(256) void k_cvt2d4(const float* __restrict__ src, int rows, int cols,
                                                bf16_t* __restrict__ dst, int dld, int doff){
  int n4 = rows*cols/4;
  int c4n = cols/4;
  int i = blockIdx.x*blockDim.x + threadIdx.x;
  int stride = gridDim.x*blockDim.x;
  for(; i<n4; i+=stride){
    int r = i / c4n, c4 = i % c4n;
    float4 v = ((const float4*)src)[i];
    unsigned long long p = (unsigned long long)f2bf(v.x)
        | ((unsigned long long)f2bf(v.y)<<16)
        | ((unsigned long long)f2bf(v.z)<<32)
        | ((unsigned long long)f2bf(v.w)<<48);
    *(unsigned long long*)(dst + (size_t)r*dld + doff + c4*4) = p;
  }
}

// ---------------- mean over P (sorted output) ----------------
__global__ __launch_bounds__(256) void k_mean(const float* __restrict__ enc, const int* __restrict__ order,
                                              bf16_t* __restrict__ me_s){
  int bs = blockIdx.x; int ec = blockIdx.y; int e = ec*256 + threadIdx.x;
  int ob = order[bs];
  const float* p = enc + (size_t)ob*NP*NE + e;
  float acc=0.f;
  for(int q=0;q<NP;q++) acc += p[(size_t)q*NE];
  me_s[(size_t)bs*NE + e] = f2bf(acc * (1.0f/NP));
}

// ---------------- big GEMM (128x128 tiles): MODE0=att1(bf16 out), MODE2=preds(f32 out, masked) ----------------
template<int MODE>
__global__ __launch_bounds__(256) void k_big(const bf16_t* __restrict__ A, int lda, int Kdim,
      const bf16_t* __restrict__ Bw, int nrowsB,
      const float* __restrict__ bias, float* __restrict__ outf, bf16_t* __restrict__ outb,
      const int* __restrict__ dlen){
  __shared__ bf16_t As[128][72];
  __shared__ bf16_t Bs[128][72];
  int mblk = blockIdx.x, nblk = blockIdx.y;
  int tid = threadIdx.x;
  int w = tid>>6, l = tid&63;
  int moff = (w>>1)*64, noff = (w&1)*64;
  f32x4 acc[4][4] = {};
  const int mbase = mblk*128, nbase = nblk*128;
  for(int k0=0; k0<Kdim; k0+=64){
    __syncthreads();
    for(int u=0;u<4;u++){
      int lin = u*256 + tid; int row = lin>>3; int col = (lin&7)*8;
      *(bf16x8*)(&As[row][col]) = *(const bf16x8*)(A + (size_t)(mbase+row)*lda + k0 + col);
      int rB = nbase+row; if(MODE==2 && rB >= nrowsB) rB = nrowsB-1;
      *(bf16x8*)(&Bs[row][col]) = *(const bf16x8*)(Bw + (size_t)rB*lda + k0 + col);
    }
    __syncthreads();
    for(int kk=0;kk<2;kk++){
      bf16x8 af[4], bfr[4];
      for(int m=0;m<4;m++) af[m] = *(bf16x8*)(&As[moff + 16*m + (l&15)][kk*32 + (l>>4)*8]);
      for(int n=0;n<4;n++) bfr[n] = *(bf16x8*)(&Bs[noff + 16*n + (l&15)][kk*32 + (l>>4)*8]);
      for(int m=0;m<4;m++)
        for(int n=0;n<4;n++)
          acc[m][n] = __builtin_amdgcn_mfma_f32_16x16x32_bf16(af[m], bfr[n], acc[m][n], 0,0,0);
    }
  }
  if(MODE==0){
    for(int m=0;m<4;m++) for(int n=0;n<4;n++){
      int col = nbase + noff + 16*n + (l&15);
      float bi = bias[col];
      for(int r=0;r<4;r++){
        int row = mbase + moff + 16*m + (l>>4)*4 + r;
        outb[(size_t)row*512 + col] = f2bf(acc[m][n][r] + bi);
      }
    }
  } else {
    for(int m=0;m<4;m++) for(int n=0;n<4;n++){
      int col = nbase + noff + 16*n + (l&15);
      if(col < NV){
        float bi = bias[col];
        for(int r=0;r<4;r++){
          int row = mbase + moff + 16*m + (l>>4)*4 + r;
          if(row < NT*NB){
            int tt = row>>6, bb = row&63;
            float val = acc[m][n][r] + bi;
            outf[((size_t)bb*NT + tt)*NV + col] = (tt < dlen[bb]) ? val : 0.f;
          }
        }
      }
    }
  }
}

// ---------------- small-M (64) GEMM with K-split: partials ----------------
template<int KSL>
__global__ __launch_bounds__(256) void k_gemm_part(const bf16_t* __restrict__ Ax, int lda,
        const bf16_t* __restrict__ W, int ldw, float* __restrict__ part, int N){
  __shared__ bf16_t As[64][KSL+8];
  int ntile = blockIdx.x, ks = blockIdx.y;
  int tid = threadIdx.x; int w = tid>>6, l = tid&63;
  int k0 = ks*KSL;
  constexpr int UPR = KSL/8;
  constexpr int UPT = 64*UPR/256;
  for(int u=0;u<UPT;u++){
    int lin = u*256 + tid; int row = lin/UPR; int col = (lin%UPR)*8;
    *(bf16x8*)(&As[row][col]) = *(const bf16x8*)(Ax + (size_t)row*lda + k0 + col);
  }
  __syncthreads();
  f32x4 acc[4][4] = {};
  int nbase = ntile*256 + w*64;
  for(int kk=0; kk<KSL/32; kk++){
    bf16x8 af[4], bfr[4];
    for(int m=0;m<4;m++) af[m] = *(bf16x8*)(&As[16*m + (l&15)][kk*32 + (l>>4)*8]);
    for(int n=0;n<4;n++) bfr[n] = *(const bf16x8*)(W + (size_t)(nbase + 16*n + (l&15))*ldw + k0 + kk*32 + (l>>4)*8);
    for(int m=0;m<4;m++)
      for(int n=0;n<4;n++)
        acc[m][n] = __builtin_amdgcn_mfma_f32_16x16x32_bf16(af[m], bfr[n], acc[m][n], 0,0,0);
  }
  float* po = part + (size_t)ks*64*N;
  for(int m=0;m<4;m++) for(int n=0;n<4;n++){
    int col = nbase + 16*n + (l&15);
    for(int r=0;r<4;r++){
      int row = 16*m + (l>>4)*4 + r;
      po[(size_t)row*N + col] = acc[m][n][r];
    }
  }
}

// ---------------- combine init partials -> h0, c0 ----------------
__global__ __launch_bounds__(256) void k_init_fin(const float* __restrict__ part,
        const float* __restrict__ b_ih_, const float* __restrict__ b_ic_,
        float* __restrict__ c, bf16_t* __restrict__ xh){
  int idx = blockIdx.x*256 + threadIdx.x;  // 0..32767
  int b_ = idx>>9, d = idx&511;
  float h = b_ih_[d], cc = b_ic_[d];
  for(int ks=0;ks<4;ks++){
    const float* p = part + (size_t)ks*64*1024 + (size_t)b_*1024;
    h += p[d]; cc += p[512+d];
  }
  c[idx] = cc;
  xh[(size_t)b_*3072 + 2560 + d] = f2bf(h);
}

// ---------------- LSTM cell ----------------
__global__ __launch_bounds__(256) void k_cell(const float* __restrict__ part,
        const float* __restrict__ b_ih, const float* __restrict__ b_hh,
        float* __restrict__ c, bf16_t* __restrict__ xh, bf16_t* __restrict__ h2all,
        const int* __restrict__ dlen, int t){
  int idx = blockIdx.x*256 + threadIdx.x; // 0..32767
  int b_ = idx>>9, d = idx&511;
  float gi = b_ih[d] + b_hh[d];
  float gf = b_ih[512+d] + b_hh[512+d];
  float gg = b_ih[1024+d] + b_hh[1024+d];
  float go = b_ih[1536+d] + b_hh[1536+d];
  for(int ks=0;ks<8;ks++){
    const float* p = part + (size_t)ks*64*2048 + (size_t)b_*2048;
    gi += p[d]; gf += p[512+d]; gg += p[1024+d]; go += p[1536+d];
  }
  float c2 = sigm(gf)*c[idx] + sigm(gi)*tanhf(gg);
  float h2 = sigm(go)*tanhf(c2);
  if(t < dlen[b_]){
    c[idx] = c2;
    xh[(size_t)b_*3072 + 2560 + d] = f2bf(h2);
  }
  h2all[((size_t)t*NB + b_)*512 + d] = f2bf(h2);
}

// ---------------- attention scores e[b][p] + emb staging ----------------
__global__ __launch_bounds__(256) void k_e(const bf16_t* __restrict__ att1b,
    const float* __restrict__ a2gp, const float* __restrict__ b_da,
    const float* __restrict__ w_fa, const float* __restrict__ b_fa,
    const int* __restrict__ order, const int* __restrict__ nact, const int* __restrict__ caps_s,
    const float* __restrict__ emb_table, float* __restrict__ e_out, bf16_t* __restrict__ xh, int t){
  int b_ = blockIdx.x, y = blockIdx.y, tid = threadIdx.x;
  if(b_ >= nact[t]) return;
  __shared__ float att2s[512];
  __shared__ float wfas[512];
  for(int i=tid;i<512;i+=256){
    att2s[i] = a2gp[(size_t)b_*2560 + i] + a2gp[(size_t)NB*2560 + (size_t)b_*2560 + i] + b_da[i];
    wfas[i] = w_fa[i];
  }
  if(y==0){
    int cap = caps_s[b_*NL + t];
    for(int d=tid; d<512; d+=256)
      xh[(size_t)b_*3072 + d] = f2bf(emb_table[(size_t)cap*512 + d]);
  }
  __syncthreads();
  int w = tid>>6, l = tid&63;
  int ob = order[b_];
  float bfa0 = b_fa[0];
  for(int pl=w; pl<49; pl+=4){
    int p = y*49 + pl;
    const bf16_t* a1 = att1b + ((size_t)ob*NP + p)*512;
    float s = 0.f;
    #pragma unroll
    for(int q=0;q<8;q++){
      int i = l + q*64;
      float v = bf2f(a1[i]) + att2s[i];
      v = v>0.f ? v : 0.f;
      s += v*wfas[i];
    }
    for(int off=32;off;off>>=1) s += __shfl_down(s, off);
    if(l==0) e_out[b_*NP + p] = s + bfa0;
  }
}

// ---------------- softmax (per-block, redundant) + awe ----------------
__global__ __launch_bounds__(256) void k_awe(const bf16_t* __restrict__ encb, const float* __restrict__ e_in,
   const float* __restrict__ a2gp, const float* __restrict__ b_fb,
   const int* __restrict__ order, const int* __restrict__ nact,
   float* __restrict__ alphas_out, bf16_t* __restrict__ xh, int t){
  int b_ = blockIdx.x, y = blockIdx.y, tid = threadIdx.x;
  bool active = b_ < nact[t];
  if(!active){
    if(y==0) for(int i=tid;i<NP;i+=256) alphas_out[((size_t)b_*NT + t)*NP + i] = 0.f;
    return;
  }
  __shared__ float al[NP];
  __shared__ float red[8];
  int w = tid>>6, l = tid&63;
  float v = (tid<NP)? e_in[b_*NP + tid] : -1e30f;
  float m = v;
  for(int off=32;off;off>>=1) m = fmaxf(m, __shfl_down(m, off));
  if(l==0) red[w] = m;
  __syncthreads();
  if(tid==0){ red[4] = fmaxf(fmaxf(red[0],red[1]), fmaxf(red[2],red[3])); }
  __syncthreads();
  float mx = red[4];
  float ex = (tid<NP)? expf(v - mx) : 0.f;
  float s2 = ex;
  for(int off=32;off;off>>=1) s2 += __shfl_down(s2, off);
  if(l==0) red[w] = s2;
  __syncthreads();
  if(tid==0){ red[5] = 1.f/(red[0]+red[1]+red[2]+red[3]); }
  __syncthreads();
  float inv = red[5];
  if(tid<NP){
    float a = ex*inv;
    al[tid] = a;
    if(y==0) alphas_out[((size_t)b_*NT + t)*NP + tid] = a;
  }
  __syncthreads();
  int ob = order[b_];
  int j = y*512 + tid*2;
  const bf16_t* ep = encb + (size_t)ob*NP*NE + j;
  float a0=0.f, a1=0.f;
  #pragma unroll 4
  for(int p=0;p<NP;p++){
    unsigned int u = *(const unsigned int*)(ep + (size_t)p*NE);
    float alp = al[p];
    a0 += alp*__uint_as_float(u<<16);
    a1 += alp*__uint_as_float(u & 0xffff0000u);
  }
  int jj = 512 + j;
  float g0 = sigm(a2gp[(size_t)b_*2560 + jj]   + a2gp[(size_t)NB*2560 + (size_t)b_*2560 + jj]   + b_fb[j]);
  float g1 = sigm(a2gp[(size_t)b_*2560 + jj+1] + a2gp[(size_t)NB*2560 + (size_t)b_*2560 + jj+1] + b_fb[j+1]);
  xh[(size_t)b_*3072 + 512 + j]     = f2bf(g0*a0);
  xh[(size_t)b_*3072 + 512 + j + 1] = f2bf(g1*a1);
}

// ---------------- launcher ----------------
extern "C" void kernel_launch(void* const* d_in, const int* in_sizes, int n_in,
                              void* d_out, int out_size, void* d_ws, size_t ws_size,
                              hipStream_t stream){
  (void)in_sizes; (void)n_in; (void)out_size; (void)ws_size;
  const float* encoder_out      = (const float*)d_in[0];
  const int*   encoded_captions = (const int*)d_in[1];
  const int*   caption_lengths  = (const int*)d_in[2];
  const float* W_ea = (const float*)d_in[3];  const float* b_ea = (const float*)d_in[4];
  const float* W_da = (const float*)d_in[5];  const float* b_da = (const float*)d_in[6];
  const float* w_fa = (const float*)d_in[7];  const float* b_fa = (const float*)d_in[8];
  const float* emb_table = (const float*)d_in[9];
  const float* W_ih = (const float*)d_in[10]; const float* b_ih = (const float*)d_in[11];
  const float* W_hh = (const float*)d_in[12]; const float* b_hh = (const float*)d_in[13];
  const float* W_init_h = (const float*)d_in[14]; const float* b_init_h = (const float*)d_in[15];
  const float* W_init_c = (const float*)d_in[16]; const float* b_init_c = (const float*)d_in[17];
  const float* W_fb = (const float*)d_in[18]; const float* b_fb = (const float*)d_in[19];
  const float* W_fc = (const float*)d_in[20]; const float* b_fc = (const float*)d_in[21];

  // d_out layout (all f32): preds | caps | dec_len | alphas | order
  float* out_preds = (float*)d_out;
  float* out_caps  = out_preds + (size_t)NB*NT*NV;
  float* out_dlen  = out_caps + NB*NL;
  float* out_alph  = out_dlen + NB;
  float* out_order = out_alph + (size_t)NB*NT*NP;

  char* ws = (char*)d_ws;
  size_t off = 0;
  auto alloc = [&](size_t bytes)->size_t{ size_t r = off; off += (bytes + 255) & ~(size_t)255; return r; };
  bf16_t* enc_b   = (bf16_t*)(ws + alloc((size_t)12544*2048*2));
  char*   reg_att1 = ws + alloc((size_t)12544*512*2);       // att1_b; ipart overlaps (used before att1 written)
  bf16_t* att1_b  = (bf16_t*)reg_att1;
  float*  ipart   = (float*)reg_att1;
  char*   reg_h2   = ws + alloc((size_t)3328*512*2);        // h2all; Wea_b overlaps (setup-only)
  bf16_t* h2all_b = (bf16_t*)reg_h2;
  bf16_t* Wea_b   = (bf16_t*)reg_h2;
  bf16_t* Wdafb_b = (bf16_t*)(ws + alloc((size_t)2560*512*2));
  bf16_t* Wcat_b  = (bf16_t*)(ws + alloc((size_t)2048*3072*2));
  bf16_t* Wfc_b   = (bf16_t*)(ws + alloc((size_t)10000*512*2));
  bf16_t* me_b    = (bf16_t*)(ws + alloc((size_t)64*2048*2));
  bf16_t* xh_b    = (bf16_t*)(ws + alloc((size_t)64*3072*2));
  float*  c_f     = (float*)(ws + alloc((size_t)64*512*4));
  float*  a2gp_f  = (float*)(ws + alloc((size_t)2*64*2560*4));
  float*  e_f     = (float*)(ws + alloc((size_t)64*196*4));
  char*   reg_gp   = ws + alloc((size_t)8*64*2048*4);       // gpart; Winit_b overlaps (setup-only)
  float*  gpart   = (float*)reg_gp;
  bf16_t* Winit_b = (bf16_t*)reg_gp;
  int*    order_i = (int*)(ws + alloc(64*4));
  int*    dlen_i  = (int*)(ws + alloc(64*4));
  int*    nact_i  = (int*)(ws + alloc(64*4));
  int*    caps_i  = (int*)(ws + alloc((size_t)64*52*4));

  k_sort<<<1,64,0,stream>>>(caption_lengths, encoded_captions, order_i, dlen_i, caps_i, nact_i,
                            out_caps, out_dlen, out_order);
  k_cvt4<<<2048,256,0,stream>>>(encoder_out, enc_b, 12544*2048/4);
  k_cvt4<<<512,256,0,stream>>>(W_ea, Wea_b, 512*2048/4);
  k_cvt4<<<256,256,0,stream>>>(W_da, Wdafb_b, 512*512/4);
  k_cvt4<<<512,256,0,stream>>>(W_fb, Wdafb_b + 512*512, 2048*512/4);
  k_cvt2d4<<<1024,256,0,stream>>>(W_ih, 2048, 2560, Wcat_b, 3072, 0);
  k_cvt2d4<<<512,256,0,stream>>>(W_hh, 2048, 512, Wcat_b, 3072, 2560);
  k_cvt4<<<512,256,0,stream>>>(W_init_h, Winit_b, 512*2048/4);
  k_cvt4<<<512,256,0,stream>>>(W_init_c, Winit_b + 512*2048, 512*2048/4);
  k_cvt4<<<1024,256,0,stream>>>(W_fc, Wfc_b, 10000*512/4);
  k_mean<<<dim3(64,8),256,0,stream>>>(encoder_out, order_i, me_b);
  k_gemm_part<512><<<dim3(4,4),256,0,stream>>>(me_b, 2048, Winit_b, 2048, ipart, 1024);
  k_init_fin<<<128,256,0,stream>>>(ipart, b_init_h, b_init_c, c_f, xh_b);
  k_big<0><<<dim3(98,4),256,0,stream>>>(enc_b, 2048, 2048, Wea_b, 512, b_ea, nullptr, att1_b, nullptr);
  // initial a2g from h0
  k_gemm_part<256><<<dim3(10,2),256,0,stream>>>(xh_b + 2560, 3072, Wdafb_b, 512, a2gp_f, 2560);
  for(int t=0;t<NT;t++){
    k_e<<<dim3(64,4),256,0,stream>>>(att1_b, a2gp_f, b_da, w_fa, b_fa,
                                     order_i, nact_i, caps_i, emb_table, e_f, xh_b, t);
    k_awe<<<dim3(64,4),256,0,stream>>>(enc_b, e_f, a2gp_f, b_fb, order_i, nact_i,
                                       out_alph, xh_b, t);
    k_gemm_part<384><<<dim3(8,8),256,0,stream>>>(xh_b, 3072, Wcat_b, 3072, gpart, 2048);
    k_cell<<<128,256,0,stream>>>(gpart, b_ih, b_hh, c_f, xh_b, h2all_b, dlen_i, t);
    k_gemm_part<256><<<dim3(10,2),256,0,stream>>>(xh_b + 2560, 3072, Wdafb_b, 512, a2gp_f, 2560);
  }
  // deferred preds GEMM: M=3328 (51*64 padded), N=10000 (79*128 tiles), K=512
  k_big<2><<<dim3(26,79),256,0,stream>>>(h2all_b, 512, 512, Wfc_b, NV, b_fc, out_preds, nullptr, dlen_i);
}